// Round 1
// baseline (208.186 us; speedup 1.0000x reference)
//
#include <hip/hip_runtime.h>
#include <hip/hip_bf16.h>
#include <hip/hip_fp16.h>
#include <cstddef>

// Problem constants
#define NB 2
#define QN 12240
#define SN 12240
#define MREAL 24480          // NB*QN rows
#define MPAD  24576          // 192 * 128
#define MT    192            // M tiles of 128

typedef unsigned short ushortT;
typedef unsigned int uintT;
typedef __bf16 bf16x8 __attribute__((ext_vector_type(8)));
typedef float f32x4 __attribute__((ext_vector_type(4)));
typedef float f32x2 __attribute__((ext_vector_type(2)));

__device__ __forceinline__ ushortT f2bf(float f) {
    uintT u = __float_as_uint(f);
    uintT r = u + 0x7fffu + ((u >> 16) & 1u);   // RNE
    return (ushortT)(r >> 16);
}
__device__ __forceinline__ float bf_lo(uintT u) {   // low bf16 -> f32
    return __uint_as_float(u << 16);
}
__device__ __forceinline__ float bf_hi(uintT u) {   // high bf16 -> f32
    return __uint_as_float(u & 0xffff0000u);
}

__device__ __forceinline__ void async_ld16(const ushortT* g, ushortT* l) {
    __builtin_amdgcn_global_load_lds(
        (const __attribute__((address_space(1))) unsigned int*)g,
        (__attribute__((address_space(3))) unsigned int*)l, 16, 0, 0);
}

// ---------------------------------------------------------------------------
// Merged cast kernel.
// bx in [0,3060): queries -> q_bf (bf16)
// bx in [3060,6120): src -> src_bf
// bx in [6120,7016): weight cast+transpose (W_val/W_attn/W_off/W_out)
// ---------------------------------------------------------------------------
__global__ __launch_bounds__(256) void cast_all(
    const float* __restrict__ q, const float* __restrict__ src,
    const float* __restrict__ Wval, const float* __restrict__ Wattn,
    const float* __restrict__ Woff, const float* __restrict__ Wout,
    ushortT* __restrict__ qb, ushortT* __restrict__ sb,
    ushortT* __restrict__ tval, ushortT* __restrict__ tlo,
    ushortT* __restrict__ tout)
{
    int bx = blockIdx.x;
    if (bx < 6120) {
        const int issrc = bx >= 3060;
        const size_t idx = ((size_t)(bx - (issrc ? 3060 : 0)) * 256 + threadIdx.x) * 8;
        const float* in = issrc ? src : q;
        ushortT* out = issrc ? sb : qb;
        const float4 a = *(const float4*)(in + idx);
        const float4 b = *(const float4*)(in + idx + 4);
        uint4 o;
        o.x = (uintT)f2bf(a.x) | ((uintT)f2bf(a.y) << 16);
        o.y = (uintT)f2bf(a.z) | ((uintT)f2bf(a.w) << 16);
        o.z = (uintT)f2bf(b.x) | ((uintT)f2bf(b.y) << 16);
        o.w = (uintT)f2bf(b.z) | ((uintT)f2bf(b.w) << 16);
        *(uint4*)(out + idx) = o;
        return;
    }
    bx -= 6120;
    const float* W; ushortT* T; int n, Nw, trow;
    if (bx < 256)      { W = Wval;  T = tval; n = bx;       Nw = 256; trow = n; }
    else if (bx < 384) { W = Wattn; T = tlo;  n = bx - 256; Nw = 128; trow = n; }
    else if (bx < 640) { W = Woff;  T = tlo;  n = bx - 384; Nw = 256; trow = n + 128; }
    else               { W = Wout;  T = tout; n = bx - 640; Nw = 256; trow = n; }
    const int k = threadIdx.x;
    T[(size_t)trow * 256 + k] = f2bf(W[(size_t)k * Nw + n]);
}

// ---------------------------------------------------------------------------
// Fused v + (logits|off) GEMM, LDS-staged (R5 structure), flat grid.
// bx<2: v = src@W_val -> v_bf in HEAD-MAJOR layout (n, head, s, 32ch) bf16
// bx>=2: lo = q@[W_attn;W_off] (col0=(bx-2)*128, fp32 out, Ntot=384)
// ---------------------------------------------------------------------------
__global__ __launch_bounds__(256) void gemm_vlo(
    const ushortT* __restrict__ q_bf, const ushortT* __restrict__ src_bf,
    const ushortT* __restrict__ wt_val, const ushortT* __restrict__ wt_lo,
    const float* __restrict__ b_val, const float* __restrict__ b_attn,
    const float* __restrict__ b_off,
    ushortT* __restrict__ v_bf, float* __restrict__ lo_ws)
{
    const int z = blockIdx.x >= 2;
    const int col0 = (z ? blockIdx.x - 2 : blockIdx.x) * 128;

    __shared__ __attribute__((aligned(16))) ushortT As[128 * 32];
    __shared__ __attribute__((aligned(16))) ushortT Bs[128 * 32];

    const ushortT* A  = z ? q_bf : src_bf;
    const ushortT* Bt = z ? wt_lo : wt_val;

    const int tid  = threadIdx.x;
    const int wave = tid >> 6;
    const int lane = tid & 63;
    const int row0 = blockIdx.y * 128;
    const int wr = (wave >> 1) * 64;
    const int wc = (wave & 1) * 64;

    f32x4 acc[4][4];
    #pragma unroll
    for (int i = 0; i < 4; i++)
        #pragma unroll
        for (int j = 0; j < 4; j++)
            acc[i][j] = (f32x4)0.f;

    const int srow = (lane >> 2);
    const int sk8  = (lane & 3) * 8;

    for (int k0 = 0; k0 < 256; k0 += 32) {
        #pragma unroll
        for (int j = 0; j < 2; j++) {
            const int r = wave * 32 + j * 16;
            async_ld16(A  + (size_t)(row0 + r + srow) * 256 + k0 + sk8, &As[r * 32]);
            async_ld16(Bt + (size_t)(col0 + r + srow) * 256 + k0 + sk8, &Bs[r * 32]);
        }
        __syncthreads();

        bf16x8 af[4], bfr[4];
        const int mrow = lane & 15;
        const int kq   = (lane >> 4) * 8;
        #pragma unroll
        for (int i = 0; i < 4; i++) {
            af[i]  = *(const bf16x8*)&As[(wr + i * 16 + mrow) * 32 + kq];
            bfr[i] = *(const bf16x8*)&Bs[(wc + i * 16 + mrow) * 32 + kq];
        }
        #pragma unroll
        for (int i = 0; i < 4; i++)
            #pragma unroll
            for (int j = 0; j < 4; j++)
                acc[i][j] = __builtin_amdgcn_mfma_f32_16x16x32_bf16(
                    af[i], bfr[j], acc[i][j], 0, 0, 0);
        __syncthreads();
    }

    const float* bp = z ? ((col0 < 128) ? b_attn : b_off) : b_val;
    const int cofs  = (z && col0 >= 128) ? 128 : 0;

    #pragma unroll
    for (int i = 0; i < 4; i++) {
        const int rbase = row0 + wr + i * 16 + ((lane >> 4) << 2);
        #pragma unroll
        for (int j = 0; j < 4; j++) {
            const int col = col0 + wc + j * 16 + (lane & 15);
            const float bb = bp[col - cofs];
            #pragma unroll
            for (int r = 0; r < 4; r++) {
                const int row = rbase + r;
                if (row < MREAL) {
                    const float val = acc[i][j][r] + bb;
                    if (z) {
                        lo_ws[(size_t)row * 384 + col] = val;
                    } else {
                        // head-major v: (n, head, s, ch)
                        const int nn = row / SN;
                        const int s  = row - nn * SN;
                        const int head = col >> 5, ch = col & 31;
                        v_bf[(((size_t)nn * 8 + head) * SN + s) * 32 + ch] = f2bf(val);
                    }
                }
            }
        }
    }
}

// ---------------------------------------------------------------------------
// Out GEMM (R5 LDS structure): out = mdv(bf16) @ wt_out^T + b_out (fp32).
// ---------------------------------------------------------------------------
__global__ __launch_bounds__(256) void gemm_out(
    const ushortT* __restrict__ A, const ushortT* __restrict__ Bt,
    const float* __restrict__ bias, float* __restrict__ C)
{
    __shared__ __attribute__((aligned(16))) ushortT As[128 * 32];
    __shared__ __attribute__((aligned(16))) ushortT Bs[128 * 32];

    const int tid  = threadIdx.x;
    const int wave = tid >> 6;
    const int lane = tid & 63;
    const int row0 = blockIdx.y * 128;
    const int col0 = blockIdx.x * 128;
    const int wr = (wave >> 1) * 64;
    const int wc = (wave & 1) * 64;

    f32x4 acc[4][4];
    #pragma unroll
    for (int i = 0; i < 4; i++)
        #pragma unroll
        for (int j = 0; j < 4; j++)
            acc[i][j] = (f32x4)0.f;

    const int srow = (lane >> 2);
    const int sk8  = (lane & 3) * 8;

    for (int k0 = 0; k0 < 256; k0 += 32) {
        #pragma unroll
        for (int j = 0; j < 2; j++) {
            const int r = wave * 32 + j * 16;
            async_ld16(A  + (size_t)(row0 + r + srow) * 256 + k0 + sk8, &As[r * 32]);
            async_ld16(Bt + (size_t)(col0 + r + srow) * 256 + k0 + sk8, &Bs[r * 32]);
        }
        __syncthreads();

        bf16x8 af[4], bfr[4];
        const int mrow = lane & 15;
        const int kq   = (lane >> 4) * 8;
        #pragma unroll
        for (int i = 0; i < 4; i++) {
            af[i]  = *(const bf16x8*)&As[(wr + i * 16 + mrow) * 32 + kq];
            bfr[i] = *(const bf16x8*)&Bs[(wc + i * 16 + mrow) * 32 + kq];
        }
        #pragma unroll
        for (int i = 0; i < 4; i++)
            #pragma unroll
            for (int j = 0; j < 4; j++)
                acc[i][j] = __builtin_amdgcn_mfma_f32_16x16x32_bf16(
                    af[i], bfr[j], acc[i][j], 0, 0, 0);
        __syncthreads();
    }

    #pragma unroll
    for (int i = 0; i < 4; i++) {
        const int rbase = row0 + wr + i * 16 + ((lane >> 4) << 2);
        #pragma unroll
        for (int j = 0; j < 4; j++) {
            const int col = col0 + wc + j * 16 + (lane & 15);
            const float bb = bias[col];
            #pragma unroll
            for (int r = 0; r < 4; r++) {
                const int row = rbase + r;
                if (row < MREAL)
                    C[(size_t)row * 256 + col] = acc[i][j][r] + bb;
            }
        }
    }
}

// ---------------------------------------------------------------------------
// Per-head two-phase sample kernel. Block = 128 threads = 2 waves =
// 16 queries of ONE head (grid: 765 x 8 heads x 2 batch). The v gather
// working set per head-plane is 0.78 MB (fits XCD L2); co-resident blocks
// share a head (head = blockIdx.y, slow dim) -> gathers are L2 hits.
// Phase 1 (lane=(qi,p)): softmax via shfl over 8 p-lanes; per point ONE
//   48B LDS record {int4 fully-resolved byte offsets,
//                   float4 {w00,w00,w10,w10}, float4 {w01,w01,w11,w11}}.
//   All per-point work (corner addr resolution, weight scaling) done ONCE
//   here instead of by each of the 8 c-lanes in phase 2.
// Phase 2 (lane=(qi,c)): per point 3x ds_read_b128 (broadcast over c;
//   qi stride = 196 ints = 4 banks -> b128 reads tile all 32 banks,
//   conflict-free), 4x 8B gathers via 32-bit offsets off a uniform base
//   (saddr form), then 8x v_pk_fma_f32 on pre-duplicated f32 weight pairs.
// ---------------------------------------------------------------------------
__global__ __launch_bounds__(128) void sample_kernel(
    const float* __restrict__ lo,       // (N*Q, 384): [0,128) logits, [128,384) off
    const float* __restrict__ geom,     // (N*Q, 4)
    const ushortT* __restrict__ v,      // (N, 8, S, 32) bf16 head-major
    ushortT* __restrict__ out)          // (N*Q, 256) bf16 mdv
{
    const int tid  = threadIdx.x;
    const int w    = tid >> 6;          // wave 0/1
    const int lane = tid & 63;
    const int qi   = lane >> 3;         // query within wave's 8
    const int m    = blockIdx.y;        // head
    const int n    = blockIdx.z;
    const int q    = blockIdx.x * 16 + w * 8 + qi;

    // per query: 16 points * 12 ints + 4 pad = 196 ints (stride = 4 banks)
    __shared__ __attribute__((aligned(16))) int pls[2][1568];   // 12544 B

    const size_t qb = (size_t)n * QN + q;

    // ---- phase 1 ----
    {
        const int p = lane & 7;                  // point pair 0..7
        const float* lorow = lo + qb * 384;
        const float2 lg = *(const float2*)(lorow + m * 16 + p * 2);
        const float4 of = *(const float4*)(lorow + 128 + m * 32 + p * 4);
        const float4 g  = *(const float4*)(geom + qb * 4);

        float mx = fmaxf(lg.x, lg.y);
        mx = fmaxf(mx, __shfl_xor(mx, 1));
        mx = fmaxf(mx, __shfl_xor(mx, 2));
        mx = fmaxf(mx, __shfl_xor(mx, 4));
        const float e0 = __expf(lg.x - mx);
        const float e1 = __expf(lg.y - mx);
        float s = e0 + e1;
        s += __shfl_xor(s, 1);
        s += __shfl_xor(s, 2);
        s += __shfl_xor(s, 4);
        const float inv = 1.f / s;

        const int l  = p >> 1;
        const int Wl = 96 >> l;
        const int s0 = (l == 0) ? 0 : (l == 1) ? 9216 : (l == 2) ? 11520 : 12096;
        const float cx = g.x, cy = g.y;
        const float sx = g.z * 0.125f, sy = g.w * 0.125f;
        int* myrec = &pls[w][qi * 196 + p * 24];

        #pragma unroll
        for (int t = 0; t < 2; t++) {
            const float ox = t ? of.z : of.x;
            const float oy = t ? of.w : of.y;
            const float wa = (t ? e1 : e0) * inv;

            const float x = (cx + ox * sx) * (float)Wl - 0.5f;
            const float y = (cy + oy * sy) * (float)Wl - 0.5f;
            const float xf = floorf(x), yf = floorf(y);
            const int x0 = (int)xf, y0 = (int)yf;
            const float wx = x - xf, wy = y - yf;

            const bool vx0 = (x0 >= 0) & (x0 < Wl);
            const bool vx1 = (x0 + 1 >= 0) & (x0 + 1 < Wl);
            const bool vy0 = (y0 >= 0) & (y0 < Wl);
            const bool vy1 = (y0 + 1 >= 0) & (y0 + 1 < Wl);

            const float w00 = (vx0 & vy0) ? wa * (1.f - wx) * (1.f - wy) : 0.f;
            const float w10 = (vx1 & vy0) ? wa * wx * (1.f - wy) : 0.f;
            const float w01 = (vx0 & vy1) ? wa * (1.f - wx) * wy : 0.f;
            const float w11 = (vx1 & vy1) ? wa * wx * wy : 0.f;

            const int xc0 = min(max(x0, 0), Wl - 1);
            const int xc1 = min(max(x0 + 1, 0), Wl - 1);
            const int yc0 = min(max(y0, 0), Wl - 1);
            const int yc1 = min(max(y0 + 1, 0), Wl - 1);

            const int o00 = (s0 + yc0 * Wl + xc0) << 6;     // byte off, row 64B
            const int dx  = (xc1 - xc0) << 6;               // 0 or 64
            const int dy  = ((yc1 - yc0) * Wl) << 6;        // 0..6144

            int4 offs;
            offs.x = o00;
            offs.y = o00 + dx;
            offs.z = o00 + dy;
            offs.w = o00 + dy + dx;
            float4 wab, wcd;
            wab.x = w00; wab.y = w00; wab.z = w10; wab.w = w10;
            wcd.x = w01; wcd.y = w01; wcd.z = w11; wcd.w = w11;

            int* rp = myrec + t * 12;
            *(int4*)rp = offs;
            *(float4*)(rp + 4) = wab;
            *(float4*)(rp + 8) = wcd;
        }
    }
    __syncthreads();

    // ---- phase 2 ----
    const int c  = lane & 7;            // channel quad within head
    const unsigned c8 = (unsigned)(c * 8);
    const unsigned char* vp = (const unsigned char*)
        (v + ((size_t)(n * 8 + m) * SN) * 32);              // uniform base
    const int* grec = &pls[w][qi * 196];

    f32x2 acc01 = (f32x2)0.f, acc23 = (f32x2)0.f;

    #pragma unroll
    for (int lk = 0; lk < 16; lk++) {
        const int* r = grec + lk * 12;
        const int4 offs = *(const int4*)r;
        const f32x2* wp = (const f32x2*)(r + 4);            // 4 duplicated pairs

        const uint2 u0 = *(const uint2*)(vp + ((unsigned)offs.x + c8));
        const uint2 u1 = *(const uint2*)(vp + ((unsigned)offs.y + c8));
        const uint2 u2 = *(const uint2*)(vp + ((unsigned)offs.z + c8));
        const uint2 u3 = *(const uint2*)(vp + ((unsigned)offs.w + c8));

        const f32x2 w0 = wp[0], w1 = wp[1], w2 = wp[2], w3 = wp[3];

        f32x2 t;
        t.x = bf_lo(u0.x); t.y = bf_hi(u0.x); acc01 += w0 * t;
        t.x = bf_lo(u0.y); t.y = bf_hi(u0.y); acc23 += w0 * t;
        t.x = bf_lo(u1.x); t.y = bf_hi(u1.x); acc01 += w1 * t;
        t.x = bf_lo(u1.y); t.y = bf_hi(u1.y); acc23 += w1 * t;
        t.x = bf_lo(u2.x); t.y = bf_hi(u2.x); acc01 += w2 * t;
        t.x = bf_lo(u2.y); t.y = bf_hi(u2.y); acc23 += w2 * t;
        t.x = bf_lo(u3.x); t.y = bf_hi(u3.x); acc01 += w3 * t;
        t.x = bf_lo(u3.y); t.y = bf_hi(u3.y); acc23 += w3 * t;
    }

    ushort4 o;
    o.x = f2bf(acc01.x); o.y = f2bf(acc01.y); o.z = f2bf(acc23.x); o.w = f2bf(acc23.y);
    *(ushort4*)(out + qb * 256 + m * 32 + c * 4) = o;
}

// ---------------------------------------------------------------------------
extern "C" void kernel_launch(void* const* d_in, const int* in_sizes, int n_in,
                              void* d_out, int out_size, void* d_ws, size_t ws_size,
                              hipStream_t stream)
{
    const float* queries = (const float*)d_in[0];
    const float* geom    = (const float*)d_in[1];
    const float* src     = (const float*)d_in[2];
    const float* W_off   = (const float*)d_in[3];
    const float* b_off   = (const float*)d_in[4];
    const float* W_attn  = (const float*)d_in[5];
    const float* b_attn  = (const float*)d_in[6];
    const float* W_val   = (const float*)d_in[7];
    const float* b_val   = (const float*)d_in[8];
    const float* W_out   = (const float*)d_in[9];
    const float* b_out   = (const float*)d_in[10];
    float* out = (float*)d_out;

    ushortT* wsb = (ushortT*)d_ws;
    const size_t PADROW = (size_t)MPAD * 256;          // 6,291,456 elems
    ushortT* q_bf    = wsb;
    ushortT* srcmdv  = wsb + PADROW;                   // src_bf, later mdv_bf
    ushortT* v_bf    = wsb + 2 * PADROW;               // head-major v
    ushortT* wt_val  = wsb + 3 * PADROW;               // 256*256
    ushortT* wt_lo   = wt_val + 65536;                 // 384*256
    ushortT* wt_out  = wt_lo + 98304;                  // 256*256
    float* lo_ws = (float*)(wt_out + 65536);           // 24480*384 fp32
    // total ~75.8 MB

    dim3 blk(256);

    cast_all<<<dim3(7016), blk, 0, stream>>>(
        queries, src, W_val, W_attn, W_off, W_out,
        q_bf, srcmdv, wt_val, wt_lo, wt_out);

    // bx<2: v = src@W_val -> v_bf (bf16 head-major); bx>=2: lo -> lo_ws
    gemm_vlo<<<dim3(5, MT), blk, 0, stream>>>(
        q_bf, srcmdv, wt_val, wt_lo, b_val, b_attn, b_off, v_bf, lo_ws);

    sample_kernel<<<dim3(QN / 16, 8, NB), dim3(128), 0, stream>>>(
        lo_ws, geom, v_bf, srcmdv);

    gemm_out<<<dim3(2, MT), blk, 0, stream>>>(srcmdv, wt_out, b_out, out);
}

// Round 2
// 205.672 us; speedup vs baseline: 1.0122x; 1.0122x over previous
//
#include <hip/hip_runtime.h>
#include <hip/hip_bf16.h>
#include <hip/hip_fp16.h>
#include <cstddef>

// Problem constants
#define NB 2
#define QN 12240
#define SN 12240
#define MREAL 24480          // NB*QN rows
#define MPAD  24576          // 192 * 128
#define MT    192            // M tiles of 128

typedef unsigned short ushortT;
typedef unsigned int uintT;
typedef __bf16 bf16x8 __attribute__((ext_vector_type(8)));
typedef float f32x4 __attribute__((ext_vector_type(4)));
typedef float f32x2 __attribute__((ext_vector_type(2)));

__device__ __forceinline__ ushortT f2bf(float f) {
    uintT u = __float_as_uint(f);
    uintT r = u + 0x7fffu + ((u >> 16) & 1u);   // RNE
    return (ushortT)(r >> 16);
}
__device__ __forceinline__ float bf_lo(uintT u) {   // low bf16 -> f32
    return __uint_as_float(u << 16);
}
__device__ __forceinline__ float bf_hi(uintT u) {   // high bf16 -> f32
    return __uint_as_float(u & 0xffff0000u);
}

__device__ __forceinline__ void async_ld16(const ushortT* g, ushortT* l) {
    __builtin_amdgcn_global_load_lds(
        (const __attribute__((address_space(1))) unsigned int*)g,
        (__attribute__((address_space(3))) unsigned int*)l, 16, 0, 0);
}

// ---------------------------------------------------------------------------
// Merged cast kernel.
// bx in [0,3060): queries -> q_bf (bf16)
// bx in [3060,6120): src -> src_bf
// bx in [6120,7016): weight cast+transpose (W_val/W_attn/W_off/W_out)
// ---------------------------------------------------------------------------
__global__ __launch_bounds__(256) void cast_all(
    const float* __restrict__ q, const float* __restrict__ src,
    const float* __restrict__ Wval, const float* __restrict__ Wattn,
    const float* __restrict__ Woff, const float* __restrict__ Wout,
    ushortT* __restrict__ qb, ushortT* __restrict__ sb,
    ushortT* __restrict__ tval, ushortT* __restrict__ tlo,
    ushortT* __restrict__ tout)
{
    int bx = blockIdx.x;
    if (bx < 6120) {
        const int issrc = bx >= 3060;
        const size_t idx = ((size_t)(bx - (issrc ? 3060 : 0)) * 256 + threadIdx.x) * 8;
        const float* in = issrc ? src : q;
        ushortT* out = issrc ? sb : qb;
        const float4 a = *(const float4*)(in + idx);
        const float4 b = *(const float4*)(in + idx + 4);
        uint4 o;
        o.x = (uintT)f2bf(a.x) | ((uintT)f2bf(a.y) << 16);
        o.y = (uintT)f2bf(a.z) | ((uintT)f2bf(a.w) << 16);
        o.z = (uintT)f2bf(b.x) | ((uintT)f2bf(b.y) << 16);
        o.w = (uintT)f2bf(b.z) | ((uintT)f2bf(b.w) << 16);
        *(uint4*)(out + idx) = o;
        return;
    }
    bx -= 6120;
    const float* W; ushortT* T; int n, Nw, trow;
    if (bx < 256)      { W = Wval;  T = tval; n = bx;       Nw = 256; trow = n; }
    else if (bx < 384) { W = Wattn; T = tlo;  n = bx - 256; Nw = 128; trow = n; }
    else if (bx < 640) { W = Woff;  T = tlo;  n = bx - 384; Nw = 256; trow = n + 128; }
    else               { W = Wout;  T = tout; n = bx - 640; Nw = 256; trow = n; }
    const int k = threadIdx.x;
    T[(size_t)trow * 256 + k] = f2bf(W[(size_t)k * Nw + n]);
}

// ---------------------------------------------------------------------------
// Fused v + (logits|off) GEMM, LDS-staged (R5 structure), flat grid.
// bx<2: v = src@W_val -> v_bf in HEAD-MAJOR layout (n, head, s, 32ch) bf16
// bx>=2: lo = q@[W_attn;W_off] (col0=(bx-2)*128, fp32 out, Ntot=384)
// ---------------------------------------------------------------------------
__global__ __launch_bounds__(256) void gemm_vlo(
    const ushortT* __restrict__ q_bf, const ushortT* __restrict__ src_bf,
    const ushortT* __restrict__ wt_val, const ushortT* __restrict__ wt_lo,
    const float* __restrict__ b_val, const float* __restrict__ b_attn,
    const float* __restrict__ b_off,
    ushortT* __restrict__ v_bf, float* __restrict__ lo_ws)
{
    const int z = blockIdx.x >= 2;
    const int col0 = (z ? blockIdx.x - 2 : blockIdx.x) * 128;

    __shared__ __attribute__((aligned(16))) ushortT As[128 * 32];
    __shared__ __attribute__((aligned(16))) ushortT Bs[128 * 32];

    const ushortT* A  = z ? q_bf : src_bf;
    const ushortT* Bt = z ? wt_lo : wt_val;

    const int tid  = threadIdx.x;
    const int wave = tid >> 6;
    const int lane = tid & 63;
    const int row0 = blockIdx.y * 128;
    const int wr = (wave >> 1) * 64;
    const int wc = (wave & 1) * 64;

    f32x4 acc[4][4];
    #pragma unroll
    for (int i = 0; i < 4; i++)
        #pragma unroll
        for (int j = 0; j < 4; j++)
            acc[i][j] = (f32x4)0.f;

    const int srow = (lane >> 2);
    const int sk8  = (lane & 3) * 8;

    for (int k0 = 0; k0 < 256; k0 += 32) {
        #pragma unroll
        for (int j = 0; j < 2; j++) {
            const int r = wave * 32 + j * 16;
            async_ld16(A  + (size_t)(row0 + r + srow) * 256 + k0 + sk8, &As[r * 32]);
            async_ld16(Bt + (size_t)(col0 + r + srow) * 256 + k0 + sk8, &Bs[r * 32]);
        }
        __syncthreads();

        bf16x8 af[4], bfr[4];
        const int mrow = lane & 15;
        const int kq   = (lane >> 4) * 8;
        #pragma unroll
        for (int i = 0; i < 4; i++) {
            af[i]  = *(const bf16x8*)&As[(wr + i * 16 + mrow) * 32 + kq];
            bfr[i] = *(const bf16x8*)&Bs[(wc + i * 16 + mrow) * 32 + kq];
        }
        #pragma unroll
        for (int i = 0; i < 4; i++)
            #pragma unroll
            for (int j = 0; j < 4; j++)
                acc[i][j] = __builtin_amdgcn_mfma_f32_16x16x32_bf16(
                    af[i], bfr[j], acc[i][j], 0, 0, 0);
        __syncthreads();
    }

    const float* bp = z ? ((col0 < 128) ? b_attn : b_off) : b_val;
    const int cofs  = (z && col0 >= 128) ? 128 : 0;

    #pragma unroll
    for (int i = 0; i < 4; i++) {
        const int rbase = row0 + wr + i * 16 + ((lane >> 4) << 2);
        #pragma unroll
        for (int j = 0; j < 4; j++) {
            const int col = col0 + wc + j * 16 + (lane & 15);
            const float bb = bp[col - cofs];
            #pragma unroll
            for (int r = 0; r < 4; r++) {
                const int row = rbase + r;
                if (row < MREAL) {
                    const float val = acc[i][j][r] + bb;
                    if (z) {
                        lo_ws[(size_t)row * 384 + col] = val;
                    } else {
                        // head-major v: (n, head, s, ch)
                        const int nn = row / SN;
                        const int s  = row - nn * SN;
                        const int head = col >> 5, ch = col & 31;
                        v_bf[(((size_t)nn * 8 + head) * SN + s) * 32 + ch] = f2bf(val);
                    }
                }
            }
        }
    }
}

// ---------------------------------------------------------------------------
// Out GEMM (R5 LDS structure): out = mdv(bf16) @ wt_out^T + b_out (fp32).
// ---------------------------------------------------------------------------
__global__ __launch_bounds__(256) void gemm_out(
    const ushortT* __restrict__ A, const ushortT* __restrict__ Bt,
    const float* __restrict__ bias, float* __restrict__ C)
{
    __shared__ __attribute__((aligned(16))) ushortT As[128 * 32];
    __shared__ __attribute__((aligned(16))) ushortT Bs[128 * 32];

    const int tid  = threadIdx.x;
    const int wave = tid >> 6;
    const int lane = tid & 63;
    const int row0 = blockIdx.y * 128;
    const int col0 = blockIdx.x * 128;
    const int wr = (wave >> 1) * 64;
    const int wc = (wave & 1) * 64;

    f32x4 acc[4][4];
    #pragma unroll
    for (int i = 0; i < 4; i++)
        #pragma unroll
        for (int j = 0; j < 4; j++)
            acc[i][j] = (f32x4)0.f;

    const int srow = (lane >> 2);
    const int sk8  = (lane & 3) * 8;

    for (int k0 = 0; k0 < 256; k0 += 32) {
        #pragma unroll
        for (int j = 0; j < 2; j++) {
            const int r = wave * 32 + j * 16;
            async_ld16(A  + (size_t)(row0 + r + srow) * 256 + k0 + sk8, &As[r * 32]);
            async_ld16(Bt + (size_t)(col0 + r + srow) * 256 + k0 + sk8, &Bs[r * 32]);
        }
        __syncthreads();

        bf16x8 af[4], bfr[4];
        const int mrow = lane & 15;
        const int kq   = (lane >> 4) * 8;
        #pragma unroll
        for (int i = 0; i < 4; i++) {
            af[i]  = *(const bf16x8*)&As[(wr + i * 16 + mrow) * 32 + kq];
            bfr[i] = *(const bf16x8*)&Bs[(wc + i * 16 + mrow) * 32 + kq];
        }
        #pragma unroll
        for (int i = 0; i < 4; i++)
            #pragma unroll
            for (int j = 0; j < 4; j++)
                acc[i][j] = __builtin_amdgcn_mfma_f32_16x16x32_bf16(
                    af[i], bfr[j], acc[i][j], 0, 0, 0);
        __syncthreads();
    }

    #pragma unroll
    for (int i = 0; i < 4; i++) {
        const int rbase = row0 + wr + i * 16 + ((lane >> 4) << 2);
        #pragma unroll
        for (int j = 0; j < 4; j++) {
            const int col = col0 + wc + j * 16 + (lane & 15);
            const float bb = bias[col];
            #pragma unroll
            for (int r = 0; r < 4; r++) {
                const int row = rbase + r;
                if (row < MREAL)
                    C[(size_t)row * 256 + col] = acc[i][j][r] + bb;
            }
        }
    }
}

// ---------------------------------------------------------------------------
// Per-head two-phase sample kernel. Block = 128 threads = 2 waves =
// 16 queries of ONE head (grid: 765 x 8 heads x 2 batch). The v gather
// working set per head-plane is 0.78 MB (fits XCD L2); co-resident blocks
// share a head (head = blockIdx.y, slow dim) -> gathers are L2 hits.
// Phase 1 (lane=(qi,p)): softmax via shfl over 8 p-lanes; per point ONE
//   48B LDS record {int4 fully-resolved byte offsets,
//                   float4 {w00,w00,w10,w10}, float4 {w01,w01,w11,w11}}.
//   Records stored in pt = t*8+p order: per-p stride 12 ints -> bank-quad
//   coefficient 3 (odd) -> consecutive lanes hit distinct quads on the
//   ds_write_b128s (fixes R1's 2-way write conflicts).
// Phase 2 (lane=(qi,c)): 4 groups of 4 points. Per group: 4x ds_read_b128
//   offsets, then ALL 16 8B gathers issued back-to-back (in-order vmcnt
//   retirement -> 16 loads in flight, latency/4 vs serial), then weights +
//   v_pk_fma_f32. All indices compile-time (no scratch).
// ---------------------------------------------------------------------------
__global__ __launch_bounds__(128) void sample_kernel(
    const float* __restrict__ lo,       // (N*Q, 384): [0,128) logits, [128,384) off
    const float* __restrict__ geom,     // (N*Q, 4)
    const ushortT* __restrict__ v,      // (N, 8, S, 32) bf16 head-major
    ushortT* __restrict__ out)          // (N*Q, 256) bf16 mdv
{
    const int tid  = threadIdx.x;
    const int w    = tid >> 6;          // wave 0/1
    const int lane = tid & 63;
    const int qi   = lane >> 3;         // query within wave's 8
    const int m    = blockIdx.y;        // head
    const int n    = blockIdx.z;
    const int q    = blockIdx.x * 16 + w * 8 + qi;

    // per query: 16 points * 12 ints + 4 pad = 196 ints (stride = 4 banks)
    __shared__ __attribute__((aligned(16))) int pls[2][1568];   // 12544 B

    const size_t qb = (size_t)n * QN + q;

    // ---- phase 1 ----
    {
        const int p = lane & 7;                  // point pair 0..7
        const float* lorow = lo + qb * 384;
        const float2 lg = *(const float2*)(lorow + m * 16 + p * 2);
        const float4 of = *(const float4*)(lorow + 128 + m * 32 + p * 4);
        const float4 g  = *(const float4*)(geom + qb * 4);

        float mx = fmaxf(lg.x, lg.y);
        mx = fmaxf(mx, __shfl_xor(mx, 1));
        mx = fmaxf(mx, __shfl_xor(mx, 2));
        mx = fmaxf(mx, __shfl_xor(mx, 4));
        const float e0 = __expf(lg.x - mx);
        const float e1 = __expf(lg.y - mx);
        float s = e0 + e1;
        s += __shfl_xor(s, 1);
        s += __shfl_xor(s, 2);
        s += __shfl_xor(s, 4);
        const float inv = 1.f / s;

        const int l  = p >> 1;
        const int Wl = 96 >> l;
        const int s0 = (l == 0) ? 0 : (l == 1) ? 9216 : (l == 2) ? 11520 : 12096;
        const float cx = g.x, cy = g.y;
        const float sx = g.z * 0.125f, sy = g.w * 0.125f;
        // record for point pt = t*8 + p lives at qi*196 + pt*12
        int* myrec = &pls[w][qi * 196 + p * 12];

        #pragma unroll
        for (int t = 0; t < 2; t++) {
            const float ox = t ? of.z : of.x;
            const float oy = t ? of.w : of.y;
            const float wa = (t ? e1 : e0) * inv;

            const float x = (cx + ox * sx) * (float)Wl - 0.5f;
            const float y = (cy + oy * sy) * (float)Wl - 0.5f;
            const float xf = floorf(x), yf = floorf(y);
            const int x0 = (int)xf, y0 = (int)yf;
            const float wx = x - xf, wy = y - yf;

            const bool vx0 = (x0 >= 0) & (x0 < Wl);
            const bool vx1 = (x0 + 1 >= 0) & (x0 + 1 < Wl);
            const bool vy0 = (y0 >= 0) & (y0 < Wl);
            const bool vy1 = (y0 + 1 >= 0) & (y0 + 1 < Wl);

            const float w00 = (vx0 & vy0) ? wa * (1.f - wx) * (1.f - wy) : 0.f;
            const float w10 = (vx1 & vy0) ? wa * wx * (1.f - wy) : 0.f;
            const float w01 = (vx0 & vy1) ? wa * (1.f - wx) * wy : 0.f;
            const float w11 = (vx1 & vy1) ? wa * wx * wy : 0.f;

            const int xc0 = min(max(x0, 0), Wl - 1);
            const int xc1 = min(max(x0 + 1, 0), Wl - 1);
            const int yc0 = min(max(y0, 0), Wl - 1);
            const int yc1 = min(max(y0 + 1, 0), Wl - 1);

            const int o00 = (s0 + yc0 * Wl + xc0) << 6;     // byte off, row 64B
            const int dx  = (xc1 - xc0) << 6;               // 0 or 64
            const int dy  = ((yc1 - yc0) * Wl) << 6;        // 0..6144

            int4 offs;
            offs.x = o00;
            offs.y = o00 + dx;
            offs.z = o00 + dy;
            offs.w = o00 + dy + dx;
            float4 wab, wcd;
            wab.x = w00; wab.y = w00; wab.z = w10; wab.w = w10;
            wcd.x = w01; wcd.y = w01; wcd.z = w11; wcd.w = w11;

            int* rp = myrec + t * 96;       // pt = t*8 + p
            *(int4*)rp = offs;
            *(float4*)(rp + 4) = wab;
            *(float4*)(rp + 8) = wcd;
        }
    }
    __syncthreads();

    // ---- phase 2 ----
    const int c  = lane & 7;            // channel quad within head
    const unsigned c8 = (unsigned)(c * 8);
    const unsigned char* vp = (const unsigned char*)
        (v + ((size_t)(n * 8 + m) * SN) * 32);              // uniform base
    const int* grec = &pls[w][qi * 196];

    f32x2 acc01 = (f32x2)0.f, acc23 = (f32x2)0.f;

    #pragma unroll
    for (int g = 0; g < 4; g++) {
        const int* r0 = grec + (g * 4 + 0) * 12;
        const int* r1 = grec + (g * 4 + 1) * 12;
        const int* r2 = grec + (g * 4 + 2) * 12;
        const int* r3 = grec + (g * 4 + 3) * 12;

        // 4 offset quads from LDS
        const int4 o0 = *(const int4*)r0;
        const int4 o1 = *(const int4*)r1;
        const int4 o2 = *(const int4*)r2;
        const int4 o3 = *(const int4*)r3;

        // 16 independent gathers, issued back-to-back
        const uint2 u00 = *(const uint2*)(vp + ((unsigned)o0.x + c8));
        const uint2 u01 = *(const uint2*)(vp + ((unsigned)o0.y + c8));
        const uint2 u02 = *(const uint2*)(vp + ((unsigned)o0.z + c8));
        const uint2 u03 = *(const uint2*)(vp + ((unsigned)o0.w + c8));
        const uint2 u10 = *(const uint2*)(vp + ((unsigned)o1.x + c8));
        const uint2 u11 = *(const uint2*)(vp + ((unsigned)o1.y + c8));
        const uint2 u12 = *(const uint2*)(vp + ((unsigned)o1.z + c8));
        const uint2 u13 = *(const uint2*)(vp + ((unsigned)o1.w + c8));
        const uint2 u20 = *(const uint2*)(vp + ((unsigned)o2.x + c8));
        const uint2 u21 = *(const uint2*)(vp + ((unsigned)o2.y + c8));
        const uint2 u22 = *(const uint2*)(vp + ((unsigned)o2.z + c8));
        const uint2 u23 = *(const uint2*)(vp + ((unsigned)o2.w + c8));
        const uint2 u30 = *(const uint2*)(vp + ((unsigned)o3.x + c8));
        const uint2 u31 = *(const uint2*)(vp + ((unsigned)o3.y + c8));
        const uint2 u32 = *(const uint2*)(vp + ((unsigned)o3.z + c8));
        const uint2 u33 = *(const uint2*)(vp + ((unsigned)o3.w + c8));

        // weights (duplicated f32 pairs) + FMAs per record
        {
            const f32x2* wp = (const f32x2*)(r0 + 4);
            const f32x2 wA = wp[0], wB = wp[1], wC = wp[2], wD = wp[3];
            f32x2 t;
            t.x = bf_lo(u00.x); t.y = bf_hi(u00.x); acc01 += wA * t;
            t.x = bf_lo(u00.y); t.y = bf_hi(u00.y); acc23 += wA * t;
            t.x = bf_lo(u01.x); t.y = bf_hi(u01.x); acc01 += wB * t;
            t.x = bf_lo(u01.y); t.y = bf_hi(u01.y); acc23 += wB * t;
            t.x = bf_lo(u02.x); t.y = bf_hi(u02.x); acc01 += wC * t;
            t.x = bf_lo(u02.y); t.y = bf_hi(u02.y); acc23 += wC * t;
            t.x = bf_lo(u03.x); t.y = bf_hi(u03.x); acc01 += wD * t;
            t.x = bf_lo(u03.y); t.y = bf_hi(u03.y); acc23 += wD * t;
        }
        {
            const f32x2* wp = (const f32x2*)(r1 + 4);
            const f32x2 wA = wp[0], wB = wp[1], wC = wp[2], wD = wp[3];
            f32x2 t;
            t.x = bf_lo(u10.x); t.y = bf_hi(u10.x); acc01 += wA * t;
            t.x = bf_lo(u10.y); t.y = bf_hi(u10.y); acc23 += wA * t;
            t.x = bf_lo(u11.x); t.y = bf_hi(u11.x); acc01 += wB * t;
            t.x = bf_lo(u11.y); t.y = bf_hi(u11.y); acc23 += wB * t;
            t.x = bf_lo(u12.x); t.y = bf_hi(u12.x); acc01 += wC * t;
            t.x = bf_lo(u12.y); t.y = bf_hi(u12.y); acc23 += wC * t;
            t.x = bf_lo(u13.x); t.y = bf_hi(u13.x); acc01 += wD * t;
            t.x = bf_lo(u13.y); t.y = bf_hi(u13.y); acc23 += wD * t;
        }
        {
            const f32x2* wp = (const f32x2*)(r2 + 4);
            const f32x2 wA = wp[0], wB = wp[1], wC = wp[2], wD = wp[3];
            f32x2 t;
            t.x = bf_lo(u20.x); t.y = bf_hi(u20.x); acc01 += wA * t;
            t.x = bf_lo(u20.y); t.y = bf_hi(u20.y); acc23 += wA * t;
            t.x = bf_lo(u21.x); t.y = bf_hi(u21.x); acc01 += wB * t;
            t.x = bf_lo(u21.y); t.y = bf_hi(u21.y); acc23 += wB * t;
            t.x = bf_lo(u22.x); t.y = bf_hi(u22.x); acc01 += wC * t;
            t.x = bf_lo(u22.y); t.y = bf_hi(u22.y); acc23 += wC * t;
            t.x = bf_lo(u23.x); t.y = bf_hi(u23.x); acc01 += wD * t;
            t.x = bf_lo(u23.y); t.y = bf_hi(u23.y); acc23 += wD * t;
        }
        {
            const f32x2* wp = (const f32x2*)(r3 + 4);
            const f32x2 wA = wp[0], wB = wp[1], wC = wp[2], wD = wp[3];
            f32x2 t;
            t.x = bf_lo(u30.x); t.y = bf_hi(u30.x); acc01 += wA * t;
            t.x = bf_lo(u30.y); t.y = bf_hi(u30.y); acc23 += wA * t;
            t.x = bf_lo(u31.x); t.y = bf_hi(u31.x); acc01 += wB * t;
            t.x = bf_lo(u31.y); t.y = bf_hi(u31.y); acc23 += wB * t;
            t.x = bf_lo(u32.x); t.y = bf_hi(u32.x); acc01 += wC * t;
            t.x = bf_lo(u32.y); t.y = bf_hi(u32.y); acc23 += wC * t;
            t.x = bf_lo(u33.x); t.y = bf_hi(u33.x); acc01 += wD * t;
            t.x = bf_lo(u33.y); t.y = bf_hi(u33.y); acc23 += wD * t;
        }
    }

    ushort4 o;
    o.x = f2bf(acc01.x); o.y = f2bf(acc01.y); o.z = f2bf(acc23.x); o.w = f2bf(acc23.y);
    *(ushort4*)(out + qb * 256 + m * 32 + c * 4) = o;
}

// ---------------------------------------------------------------------------
extern "C" void kernel_launch(void* const* d_in, const int* in_sizes, int n_in,
                              void* d_out, int out_size, void* d_ws, size_t ws_size,
                              hipStream_t stream)
{
    const float* queries = (const float*)d_in[0];
    const float* geom    = (const float*)d_in[1];
    const float* src     = (const float*)d_in[2];
    const float* W_off   = (const float*)d_in[3];
    const float* b_off   = (const float*)d_in[4];
    const float* W_attn  = (const float*)d_in[5];
    const float* b_attn  = (const float*)d_in[6];
    const float* W_val   = (const float*)d_in[7];
    const float* b_val   = (const float*)d_in[8];
    const float* W_out   = (const float*)d_in[9];
    const float* b_out   = (const float*)d_in[10];
    float* out = (float*)d_out;

    ushortT* wsb = (ushortT*)d_ws;
    const size_t PADROW = (size_t)MPAD * 256;          // 6,291,456 elems
    ushortT* q_bf    = wsb;
    ushortT* srcmdv  = wsb + PADROW;                   // src_bf, later mdv_bf
    ushortT* v_bf    = wsb + 2 * PADROW;               // head-major v
    ushortT* wt_val  = wsb + 3 * PADROW;               // 256*256
    ushortT* wt_lo   = wt_val + 65536;                 // 384*256
    ushortT* wt_out  = wt_lo + 98304;                  // 256*256
    float* lo_ws = (float*)(wt_out + 65536);           // 24480*384 fp32
    // total ~75.8 MB

    dim3 blk(256);

    cast_all<<<dim3(7016), blk, 0, stream>>>(
        queries, src, W_val, W_attn, W_off, W_out,
        q_bf, srcmdv, wt_val, wt_lo, wt_out);

    // bx<2: v = src@W_val -> v_bf (bf16 head-major); bx>=2: lo -> lo_ws
    gemm_vlo<<<dim3(5, MT), blk, 0, stream>>>(
        q_bf, srcmdv, wt_val, wt_lo, b_val, b_attn, b_off, v_bf, lo_ws);

    sample_kernel<<<dim3(QN / 16, 8, NB), dim3(128), 0, stream>>>(
        lo_ws, geom, v_bf, srcmdv);

    gemm_out<<<dim3(2, MT), blk, 0, stream>>>(srcmdv, wt_out, b_out, out);
}